// Round 9
// baseline (205.849 us; speedup 1.0000x reference)
//
#include <hip/hip_runtime.h>
#include <math.h>

#define N_ATOMS    30000
#define N_PAIRS    300000
#define CAP        48              // bucket capacity per atom; multiple of 16
#define NF         64
#define ND         20
#define K_ENV      1280            // 20nu * 64f (packed, no padding)
#define K_TOT      1344            // K_ENV + 64 self features
#define NKSTEP     42              // K_TOT / 32
#define NTILE      1875            // N_ATOMS / BA
#define NBLK       768             // persistent blocks (3/CU x 256)
#define HARD_CUT   6.5f
#define BA         16              // atoms per tile in main kernel
#define ESTRIDE    1352            // env row stride in u16 (1344+8 pad -> bank spread)
#define D_LO       0.85f
#define D_SCALE    (5.65f / 65535.0f)
#define D_SCALE_I  (65535.0f / 5.65f)

typedef short  s16x8  __attribute__((ext_vector_type(8)));
typedef __bf16 bf16x8 __attribute__((ext_vector_type(8)));
typedef float  f32x4  __attribute__((ext_vector_type(4)));
typedef float  f32x16 __attribute__((ext_vector_type(16)));

__device__ __forceinline__ unsigned short f2bf(float x) {
    union { float f; unsigned u; } v; v.f = x;
    unsigned r = v.u + 0x7fffu + ((v.u >> 16) & 1u);   // RNE
    return (unsigned short)(r >> 16);
}
// pack two floats -> packed bf16 pair (a in low 16), RNE
__device__ __forceinline__ unsigned pkbf(float a, float b) {
    return (unsigned)f2bf(a) | ((unsigned)f2bf(b) << 16);
}

// ---------------------------------------------------------------------------
// K0: prep = pack weights into bf16 B-frag layout with phase-1 k'-permutation
// (blocks 0..41), zero cnts (42..159), msr + tile counter (160).
// k' < 1280: t=k'/640, g=(k'%640)>>7, c=(k'&127)>>2, r=k'&3 -> nu=4g+r, f=2c+t
//            (even/odd feature split -> phase-1 dwordx2 gathers)
// k' >=1280: self row, f = k'-1280.
__global__ void k_prep(const float* __restrict__ iw, const float* __restrict__ wself,
                       const float* __restrict__ mu, const float* __restrict__ sigma,
                       unsigned short* __restrict__ WtB, int* __restrict__ cnts,
                       float2* __restrict__ msr, int* __restrict__ ctr) {
    if (blockIdx.x < 42) {
        int idx = blockIdx.x * 256 + threadIdx.x;       // (ks*4+q)*64 + lane
        if (idx >= NKSTEP * 4 * 64) return;
        int l  = idx & 63;
        int q  = (idx >> 6) & 3;
        int ks = idx >> 8;
        int n  = q * 16 + (l & 15);
        int kb = ks * 32 + (l >> 4) * 8;
        union { unsigned short us[8]; uint4 v; } u;
        #pragma unroll
        for (int j = 0; j < 8; j++) {
            int k = kb + j;
            float val;
            if (k < K_ENV) {
                int t  = k / 640;
                int rm = k - t * 640;
                int g  = rm >> 7;
                int c  = (rm & 127) >> 2;
                int r  = k & 3;
                int nu = 4 * g + r;
                int f  = 2 * c + t;                      // even/odd tile split
                val = iw[(nu * NF + n) * NF + f];
            } else {
                val = wself[n * NF + (k - K_ENV)];
            }
            u.us[j] = f2bf(val);
        }
        *(uint4*)&WtB[idx * 8] = u.v;
    } else if (blockIdx.x < 160) {
        int i = (blockIdx.x - 42) * 256 + threadIdx.x;
        if (i < N_ATOMS) cnts[i] = 0;
    } else {
        int i = threadIdx.x;
        if (i < ND) { float2 m; m.x = mu[i]; m.y = 1.0f / sigma[i]; msr[i] = m; }
        if (i == 0) *ctr = NBLK;                         // work-steal counter
    }
}

// ---------------------------------------------------------------------------
// K1: scatter pairs into per-atom buckets; pack (second<<16 | dist_u16).
__global__ void k_scatter(const int* __restrict__ first, const int* __restrict__ second,
                          const float* __restrict__ dist, int* __restrict__ cnts,
                          unsigned* __restrict__ pk) {
    int p = blockIdx.x * 256 + threadIdx.x;
    if (p >= N_PAIRS) return;
    int a = first[p];
    int pos = atomicAdd(&cnts[a], 1);
    if (pos < CAP) {
        float d = dist[p];
        unsigned du = (unsigned)((d - D_LO) * D_SCALE_I + 0.5f);
        du = min(du, 65535u);
        pk[(size_t)a * CAP + pos] = ((unsigned)second[p] << 16) | du;
    }
}

// ---------------------------------------------------------------------------
// K2: fused sense + MFMA envsum + MFMA interaction matmul. 512 thr = 8 waves.
// Persistent: 768 blocks work-steal 1875 tiles of 16 atoms (no dispatch tail).
// Phase 1: wave w handles atoms {2w,2w+1}. Per 16-pair K-step:
//   A = sense^T (lane nu=l&31, 8 exps packed inline -> temps die pre-MFMA),
//   B = x rows gathered as dwordx2 (features 2cl,2cl+1 -> tiles even/odd),
//   2x mfma_f32_32x32x16_bf16; C -> LDS in C-layout (k'-perm matches WtB).
// Phase 2: waves 0..3: out[16 atoms][64] = env[16][1344] x WtB (16x16x32).
__global__ void __launch_bounds__(512, 6)
k_main(const float* __restrict__ x, const int* __restrict__ cnts,
       const unsigned* __restrict__ pk, const float2* __restrict__ msr,
       const unsigned short* __restrict__ WtB, const float* __restrict__ bself,
       float* __restrict__ out, int* __restrict__ ctr) {
    __shared__ unsigned short env[BA * ESTRIDE];          // 43264 B -> 3 blocks/CU
    __shared__ int tile_s;
    const int t  = threadIdx.x;
    const int w  = t >> 6;       // wave 0..7
    const int l  = t & 63;       // lane
    const int h  = l >> 5;       // half-wave (k-group)
    const int cl = l & 31;       // A: nu row   |  B/C: column
    const int m16  = l & 15;
    const int quad = l >> 4;

    // lane-resident sense constants (nu = cl)
    float2 ms   = msr[min(cl, ND - 1)];
    const float isig  = ms.y;
    const float musig = ms.x * ms.y;
    const bool  nuok  = (cl < ND);
    const float bs = bself[(w & 3) * 16 + m16];

    int tile = blockIdx.x;
    for (;;) {
        const int a0 = tile * BA;

        // ---- Phase 1: MFMA envsum (2 atoms per wave) ----
        for (int ci = 0; ci < 2; ci++) {
            const int i = 2 * w + ci;
            const int a = a0 + i;
            const int cnt = min(cnts[a], CAP);
            const int nst = max((cnt + 15) >> 4, 1);
            const unsigned* gb = &pk[(size_t)a * CAP];
            const float selfv = x[(size_t)a * NF + l];    // hoisted (MLP)
            f32x16 acc0 = {0.f}, acc1 = {0.f};
            #pragma unroll 1
            for (int ks = 0; ks < nst; ks++) {
                const int k0 = ks * 16 + h * 8;
                uint4 p0 = *(const uint4*)(gb + k0);      // 16B-aligned, h-uniform
                uint4 p1 = *(const uint4*)(gb + k0 + 4);
                unsigned pv[8] = {p0.x, p0.y, p0.z, p0.w, p1.x, p1.y, p1.z, p1.w};
                // 8 dwordx2 gathers: features {2cl, 2cl+1} per pair
                float2 bv[8];
                #pragma unroll
                for (int j = 0; j < 8; j++) {
                    unsigned idx = min(pv[j] >> 16, (unsigned)(N_ATOMS - 1));
                    bv[j] = *(const float2*)&x[idx * NF + 2 * cl];
                }
                union { unsigned u[4]; s16x8 s; } A, B0, B1;
                #pragma unroll
                for (int j = 0; j < 4; j++) {             // sense packed inline
                    float e0, e1;
                    {
                        float d  = D_LO + (float)(pv[2 * j] & 0xffffu) * D_SCALE;
                        float z  = __builtin_amdgcn_rcpf(d) * isig - musig;
                        float co = __cosf(0.2416609733530613f * d);   // 0.5*pi/6.5
                        float e  = __expf(-0.5f * z * z) * (co * co);
                        e0 = (nuok && (k0 + 2 * j) < cnt) ? e : 0.0f;
                    }
                    {
                        float d  = D_LO + (float)(pv[2 * j + 1] & 0xffffu) * D_SCALE;
                        float z  = __builtin_amdgcn_rcpf(d) * isig - musig;
                        float co = __cosf(0.2416609733530613f * d);
                        float e  = __expf(-0.5f * z * z) * (co * co);
                        e1 = (nuok && (k0 + 2 * j + 1) < cnt) ? e : 0.0f;
                    }
                    A.u[j] = pkbf(e0, e1);
                }
                #pragma unroll
                for (int j = 0; j < 4; j++) {
                    B0.u[j] = pkbf(bv[2 * j].x, bv[2 * j + 1].x);   // even features
                    B1.u[j] = pkbf(bv[2 * j].y, bv[2 * j + 1].y);   // odd features
                }
                acc0 = __builtin_amdgcn_mfma_f32_32x32x16_bf16(
                           __builtin_bit_cast(bf16x8, A.s),
                           __builtin_bit_cast(bf16x8, B0.s), acc0, 0, 0, 0);
                acc1 = __builtin_amdgcn_mfma_f32_32x32x16_bf16(
                           __builtin_bit_cast(bf16x8, A.s),
                           __builtin_bit_cast(bf16x8, B1.s), acc1, 0, 0, 0);
            }
            // C -> env LDS. C row = (reg&3)+8*(reg>>2)+4*h; g=2q+h holds rows
            // 4g..4g+3 (g<5 <=> row<20). k' = t*640 + g*128 + cl*4 + r.
            unsigned short* er = &env[i * ESTRIDE];
            #pragma unroll
            for (int q = 0; q < 3; q++) {
                int g = 2 * q + h;
                if (g < 5) {
                    uint2 v0, v1;
                    v0.x = pkbf(acc0[4 * q + 0], acc0[4 * q + 1]);
                    v0.y = pkbf(acc0[4 * q + 2], acc0[4 * q + 3]);
                    v1.x = pkbf(acc1[4 * q + 0], acc1[4 * q + 1]);
                    v1.y = pkbf(acc1[4 * q + 2], acc1[4 * q + 3]);
                    *(uint2*)&er[g * 128 + cl * 4]       = v0;
                    *(uint2*)&er[640 + g * 128 + cl * 4] = v1;
                }
            }
            er[K_ENV + l] = f2bf(selfv);                  // self features
        }
        __syncthreads();

        // ---- Phase 2: MFMA GEMM (waves 0..3) ----
        if (w < 4) {
            f32x4 acc = {0.f, 0.f, 0.f, 0.f};
            for (int ks = 0; ks < NKSTEP; ks++) {
                s16x8 afrag = *(const s16x8*)&env[m16 * ESTRIDE + ks * 32 + quad * 8];
                s16x8 bfrag = *(const s16x8*)&WtB[((ks * 4 + w) * 64 + l) * 8];
                acc = __builtin_amdgcn_mfma_f32_16x16x32_bf16(
                          __builtin_bit_cast(bf16x8, afrag),
                          __builtin_bit_cast(bf16x8, bfrag), acc, 0, 0, 0);
            }
            #pragma unroll
            for (int r = 0; r < 4; r++) {
                int row = quad * 4 + r;                   // atom within tile
                out[(size_t)(a0 + row) * NF + w * 16 + m16] = acc[r] + bs;
            }
        }

        // ---- steal next tile (barrier also guards env reuse) ----
        if (t == 0) tile_s = atomicAdd(ctr, 1);
        __syncthreads();
        tile = tile_s;
        if (tile >= NTILE) break;
    }
}

// ---------------------------------------------------------------------------
extern "C" void kernel_launch(void* const* d_in, const int* in_sizes, int n_in,
                              void* d_out, int out_size, void* d_ws, size_t ws_size,
                              hipStream_t stream) {
    const float* x      = (const float*)d_in[0];
    const int*   first  = (const int*)d_in[1];
    const int*   second = (const int*)d_in[2];
    const float* dist   = (const float*)d_in[3];
    const float* mu     = (const float*)d_in[4];
    const float* sigma  = (const float*)d_in[5];
    const float* iw     = (const float*)d_in[6];
    const float* wself  = (const float*)d_in[7];
    const float* bself  = (const float*)d_in[8];
    float* out = (float*)d_out;

    char* ws = (char*)d_ws;
    unsigned short* WtB  = (unsigned short*)(ws);          // 172032 B
    int*            cnts = (int*)(ws + 172032);            // 120000 B
    float2*         msr  = (float2*)(ws + 292032);         // 160 B
    int*            ctr  = (int*)(ws + 292192);            // 64 B
    unsigned*       pk   = (unsigned*)(ws + 292256);       // 5760000 B -> ~6.05 MB

    k_prep<<<dim3(161), dim3(256), 0, stream>>>(iw, wself, mu, sigma, WtB, cnts, msr, ctr);
    k_scatter<<<dim3((N_PAIRS + 255) / 256), dim3(256), 0, stream>>>(
        first, second, dist, cnts, pk);
    k_main<<<dim3(NBLK), dim3(512), 0, stream>>>(
        x, cnts, pk, msr, WtB, bself, out, ctr);
}

// Round 10
// 131.198 us; speedup vs baseline: 1.5690x; 1.5690x over previous
//
#include <hip/hip_runtime.h>
#include <math.h>

#define N_ATOMS    30000
#define N_PAIRS    300000
#define CAP        48              // bucket capacity per atom; multiple of 16
#define NF         64
#define ND         20
#define K_ENV      1280            // 20nu * 64f (packed, no padding)
#define K_TOT      1344            // K_ENV + 64 self features
#define NKSTEP     42              // K_TOT / 32
#define HARD_CUT   6.5f
#define BA         16              // atoms per block in main kernel
#define ESTRIDE    1352            // env row stride in u16 (1344+8 pad -> bank spread)
#define D_LO       0.85f
#define D_SCALE    (5.65f / 65535.0f)
#define D_SCALE_I  (65535.0f / 5.65f)

typedef short  s16x8  __attribute__((ext_vector_type(8)));
typedef __bf16 bf16x8 __attribute__((ext_vector_type(8)));
typedef float  f32x4  __attribute__((ext_vector_type(4)));
typedef float  f32x16 __attribute__((ext_vector_type(16)));

__device__ __forceinline__ unsigned short f2bf(float x) {
    union { float f; unsigned u; } v; v.f = x;
    unsigned r = v.u + 0x7fffu + ((v.u >> 16) & 1u);   // RNE
    return (unsigned short)(r >> 16);
}
// pack two floats -> packed bf16 pair (a in low 16), RNE
__device__ __forceinline__ unsigned pkbf(float a, float b) {
    return (unsigned)f2bf(a) | ((unsigned)f2bf(b) << 16);
}

// ---------------------------------------------------------------------------
// K0: prep = pack weights into bf16 B-frag layout with phase-1 k'-permutation
// (blocks 0..41), zero cnts (42..159), msr (160).
// k' < 1280: t=k'/640, g=(k'%640)>>7, c=(k'&127)>>2, r=k'&3 -> nu=4g+r, f=2c+t
//            (even/odd feature split -> phase-1 dwordx2 gathers; verified R9)
// k' >=1280: self row, f = k'-1280.
__global__ void k_prep(const float* __restrict__ iw, const float* __restrict__ wself,
                       const float* __restrict__ mu, const float* __restrict__ sigma,
                       unsigned short* __restrict__ WtB, int* __restrict__ cnts,
                       float2* __restrict__ msr) {
    if (blockIdx.x < 42) {
        int idx = blockIdx.x * 256 + threadIdx.x;       // (ks*4+q)*64 + lane
        if (idx >= NKSTEP * 4 * 64) return;
        int l  = idx & 63;
        int q  = (idx >> 6) & 3;
        int ks = idx >> 8;
        int n  = q * 16 + (l & 15);
        int kb = ks * 32 + (l >> 4) * 8;
        union { unsigned short us[8]; uint4 v; } u;
        #pragma unroll
        for (int j = 0; j < 8; j++) {
            int k = kb + j;
            float val;
            if (k < K_ENV) {
                int t  = k / 640;
                int rm = k - t * 640;
                int g  = rm >> 7;
                int c  = (rm & 127) >> 2;
                int r  = k & 3;
                int nu = 4 * g + r;
                int f  = 2 * c + t;                      // even/odd tile split
                val = iw[(nu * NF + n) * NF + f];
            } else {
                val = wself[n * NF + (k - K_ENV)];
            }
            u.us[j] = f2bf(val);
        }
        *(uint4*)&WtB[idx * 8] = u.v;
    } else if (blockIdx.x < 160) {
        int i = (blockIdx.x - 42) * 256 + threadIdx.x;
        if (i < N_ATOMS) cnts[i] = 0;
    } else {
        int i = threadIdx.x;
        if (i < ND) { float2 m; m.x = mu[i]; m.y = 1.0f / sigma[i]; msr[i] = m; }
    }
}

// ---------------------------------------------------------------------------
// K1: scatter pairs into per-atom buckets; pack (second<<16 | dist_u16).
__global__ void k_scatter(const int* __restrict__ first, const int* __restrict__ second,
                          const float* __restrict__ dist, int* __restrict__ cnts,
                          unsigned* __restrict__ pk) {
    int p = blockIdx.x * 256 + threadIdx.x;
    if (p >= N_PAIRS) return;
    int a = first[p];
    int pos = atomicAdd(&cnts[a], 1);
    if (pos < CAP) {
        float d = dist[p];
        unsigned du = (unsigned)((d - D_LO) * D_SCALE_I + 0.5f);
        du = min(du, 65535u);
        pk[(size_t)a * CAP + pos] = ((unsigned)second[p] << 16) | du;
    }
}

// ---------------------------------------------------------------------------
// K2: fused sense + MFMA envsum + MFMA interaction matmul. 512 thr = 8 waves.
// Phase 1: wave w handles atoms {2w,2w+1} STRICTLY SEQUENTIALLY (unroll 1 ->
//   one atom's accumulators live at a time -> fits the (512,6) VGPR budget).
//   Per 16-pair K-step: A = sense^T (8 exps packed inline), B = x rows
//   gathered as dwordx2 (features {2cl,2cl+1} -> even/odd tiles),
//   2x mfma_f32_32x32x16_bf16; C -> LDS in C-layout (k'-perm matches WtB).
// Phase 2: waves 0..3: out[16 atoms][64] = env[16][1344] x WtB (16x16x32).
__global__ void __launch_bounds__(512, 6)
k_main(const float* __restrict__ x, const int* __restrict__ cnts,
       const unsigned* __restrict__ pk, const float2* __restrict__ msr,
       const unsigned short* __restrict__ WtB, const float* __restrict__ bself,
       float* __restrict__ out) {
    __shared__ unsigned short env[BA * ESTRIDE];          // 43264 B -> 3 blocks/CU
    const int t  = threadIdx.x;
    const int w  = t >> 6;       // wave 0..7
    const int l  = t & 63;       // lane
    const int h  = l >> 5;       // half-wave (k-group)
    const int cl = l & 31;       // A: nu row   |  B/C: column
    const int a0 = blockIdx.x * BA;

    // lane-resident sense constants (nu = cl)
    float2 ms   = msr[min(cl, ND - 1)];
    const float isig  = ms.y;
    const float musig = ms.x * ms.y;
    const bool  nuok  = (cl < ND);

    // ---- Phase 1: MFMA envsum (2 atoms per wave, sequential) ----
    #pragma unroll 1
    for (int ci = 0; ci < 2; ci++) {
        const int i = 2 * w + ci;
        const int a = a0 + i;
        const int cnt = min(cnts[a], CAP);
        const int nst = max((cnt + 15) >> 4, 1);
        const unsigned* gb = &pk[(size_t)a * CAP];
        f32x16 acc0 = {0.f}, acc1 = {0.f};
        #pragma unroll 1
        for (int ks = 0; ks < nst; ks++) {
            const int k0 = ks * 16 + h * 8;
            uint4 p0 = *(const uint4*)(gb + k0);          // 16B-aligned, h-uniform
            uint4 p1 = *(const uint4*)(gb + k0 + 4);
            unsigned pv[8] = {p0.x, p0.y, p0.z, p0.w, p1.x, p1.y, p1.z, p1.w};
            // 8 dwordx2 gathers: features {2cl, 2cl+1} per pair (MLP up front)
            float2 bv[8];
            #pragma unroll
            for (int j = 0; j < 8; j++) {
                unsigned idx = min(pv[j] >> 16, (unsigned)(N_ATOMS - 1));
                bv[j] = *(const float2*)&x[idx * NF + 2 * cl];
            }
            union { unsigned u[4]; s16x8 s; } A, B0, B1;
            #pragma unroll
            for (int j = 0; j < 4; j++) {                 // sense packed inline
                float e0, e1;
                {
                    float d  = D_LO + (float)(pv[2 * j] & 0xffffu) * D_SCALE;
                    float z  = __builtin_amdgcn_rcpf(d) * isig - musig;
                    float co = __cosf(0.2416609733530613f * d);   // 0.5*pi/6.5
                    float e  = __expf(-0.5f * z * z) * (co * co);
                    e0 = (nuok && (k0 + 2 * j) < cnt) ? e : 0.0f;
                }
                {
                    float d  = D_LO + (float)(pv[2 * j + 1] & 0xffffu) * D_SCALE;
                    float z  = __builtin_amdgcn_rcpf(d) * isig - musig;
                    float co = __cosf(0.2416609733530613f * d);
                    float e  = __expf(-0.5f * z * z) * (co * co);
                    e1 = (nuok && (k0 + 2 * j + 1) < cnt) ? e : 0.0f;
                }
                A.u[j] = pkbf(e0, e1);
            }
            #pragma unroll
            for (int j = 0; j < 4; j++) {
                B0.u[j] = pkbf(bv[2 * j].x, bv[2 * j + 1].x);   // even features
                B1.u[j] = pkbf(bv[2 * j].y, bv[2 * j + 1].y);   // odd features
            }
            acc0 = __builtin_amdgcn_mfma_f32_32x32x16_bf16(
                       __builtin_bit_cast(bf16x8, A.s),
                       __builtin_bit_cast(bf16x8, B0.s), acc0, 0, 0, 0);
            acc1 = __builtin_amdgcn_mfma_f32_32x32x16_bf16(
                       __builtin_bit_cast(bf16x8, A.s),
                       __builtin_bit_cast(bf16x8, B1.s), acc1, 0, 0, 0);
        }
        // C -> env LDS. C row = (reg&3)+8*(reg>>2)+4*h; g=2q+h holds rows
        // 4g..4g+3 (g<5 <=> row<20). k' = t*640 + g*128 + cl*4 + r.
        unsigned short* er = &env[i * ESTRIDE];
        #pragma unroll
        for (int q = 0; q < 3; q++) {
            int g = 2 * q + h;
            if (g < 5) {
                uint2 v0, v1;
                v0.x = pkbf(acc0[4 * q + 0], acc0[4 * q + 1]);
                v0.y = pkbf(acc0[4 * q + 2], acc0[4 * q + 3]);
                v1.x = pkbf(acc1[4 * q + 0], acc1[4 * q + 1]);
                v1.y = pkbf(acc1[4 * q + 2], acc1[4 * q + 3]);
                *(uint2*)&er[g * 128 + cl * 4]       = v0;
                *(uint2*)&er[640 + g * 128 + cl * 4] = v1;
            }
        }
        er[K_ENV + l] = f2bf(x[(size_t)a * NF + l]);      // self features
    }
    __syncthreads();

    // ---- Phase 2: MFMA GEMM (waves 0..3) ----
    if (w < 4) {
        const int m16  = l & 15;     // atom row / out col
        const int quad = l >> 4;
        f32x4 acc = {0.f, 0.f, 0.f, 0.f};
        for (int ks = 0; ks < NKSTEP; ks++) {
            s16x8 afrag = *(const s16x8*)&env[m16 * ESTRIDE + ks * 32 + quad * 8];
            s16x8 bfrag = *(const s16x8*)&WtB[((ks * 4 + w) * 64 + l) * 8];
            acc = __builtin_amdgcn_mfma_f32_16x16x32_bf16(
                      __builtin_bit_cast(bf16x8, afrag),
                      __builtin_bit_cast(bf16x8, bfrag), acc, 0, 0, 0);
        }
        const float bs = bself[w * 16 + m16];
        #pragma unroll
        for (int r = 0; r < 4; r++) {
            int row = quad * 4 + r;                       // atom within block
            out[(size_t)(a0 + row) * NF + w * 16 + m16] = acc[r] + bs;
        }
    }
}

// ---------------------------------------------------------------------------
extern "C" void kernel_launch(void* const* d_in, const int* in_sizes, int n_in,
                              void* d_out, int out_size, void* d_ws, size_t ws_size,
                              hipStream_t stream) {
    const float* x      = (const float*)d_in[0];
    const int*   first  = (const int*)d_in[1];
    const int*   second = (const int*)d_in[2];
    const float* dist   = (const float*)d_in[3];
    const float* mu     = (const float*)d_in[4];
    const float* sigma  = (const float*)d_in[5];
    const float* iw     = (const float*)d_in[6];
    const float* wself  = (const float*)d_in[7];
    const float* bself  = (const float*)d_in[8];
    float* out = (float*)d_out;

    char* ws = (char*)d_ws;
    unsigned short* WtB  = (unsigned short*)(ws);          // 172032 B
    int*            cnts = (int*)(ws + 172032);            // 120000 B
    float2*         msr  = (float2*)(ws + 292032);         // 160 B
    unsigned*       pk   = (unsigned*)(ws + 292192);       // 5760000 B -> ~6.05 MB

    k_prep<<<dim3(161), dim3(256), 0, stream>>>(iw, wself, mu, sigma, WtB, cnts, msr);
    k_scatter<<<dim3((N_PAIRS + 255) / 256), dim3(256), 0, stream>>>(
        first, second, dist, cnts, pk);
    k_main<<<dim3(N_ATOMS / BA), dim3(512), 0, stream>>>(
        x, cnts, pk, msr, WtB, bself, out);
}

// Round 11
// 128.308 us; speedup vs baseline: 1.6043x; 1.0225x over previous
//
#include <hip/hip_runtime.h>
#include <math.h>

#define N_ATOMS    30000
#define N_PAIRS    300000
#define CAP        48              // bucket capacity per atom; multiple of 16
#define NF         64
#define ND         20
#define K_ENV      1280            // 20nu * 64f (packed, no padding)
#define K_TOT      1344            // K_ENV + 64 self features
#define NKSTEP     42              // K_TOT / 32
#define HARD_CUT   6.5f
#define BA         16              // atoms per block in main kernel
#define ESTRIDE    1352            // env row stride in u16 (1344+8 pad -> bank spread)
#define D_LO       0.85f
#define D_SCALE    (5.65f / 65535.0f)
#define D_SCALE_I  (65535.0f / 5.65f)
#define NM1        ((unsigned)(N_ATOMS - 1))

typedef short    s16x8  __attribute__((ext_vector_type(8)));
typedef __bf16   bf16x8 __attribute__((ext_vector_type(8)));
typedef unsigned u32x4  __attribute__((ext_vector_type(4)));
typedef float    f32x4  __attribute__((ext_vector_type(4)));
typedef float    f32x16 __attribute__((ext_vector_type(16)));

__device__ __forceinline__ unsigned short f2bf(float x) {
    union { float f; unsigned u; } v; v.f = x;
    unsigned r = v.u + 0x7fffu + ((v.u >> 16) & 1u);   // RNE
    return (unsigned short)(r >> 16);
}
// pack two floats -> packed bf16 pair (a in low 16), RNE
__device__ __forceinline__ unsigned pkbf(float a, float b) {
    return (unsigned)f2bf(a) | ((unsigned)f2bf(b) << 16);
}
// sensitivity for one packed pair-slot, lane's nu
__device__ __forceinline__ float senseval(unsigned pu, int kidx, int cnt,
                                          float isig, float musig, bool nuok) {
    float d  = D_LO + (float)(pu & 0xffffu) * D_SCALE;
    float z  = __builtin_amdgcn_rcpf(d) * isig - musig;
    float co = __cosf(0.2416609733530613f * d);        // 0.5*pi/6.5
    float e  = __expf(-0.5f * z * z) * (co * co);
    return (nuok && kidx < cnt) ? e : 0.0f;
}

// ---------------------------------------------------------------------------
// K0: prep = pack weights into bf16 B-frag layout with phase-1 k'-permutation
// (blocks 0..41), zero cnts (42..159), msr (160).
// k' < 1280: t=k'/640, g=(k'%640)>>7, c=(k'&127)>>2, r=k'&3 -> nu=4g+r, f=2c+t
//            (even/odd feature split -> phase-1 dwordx2 gathers; verified R9)
// k' >=1280: self row, f = k'-1280.
__global__ void k_prep(const float* __restrict__ iw, const float* __restrict__ wself,
                       const float* __restrict__ mu, const float* __restrict__ sigma,
                       unsigned short* __restrict__ WtB, int* __restrict__ cnts,
                       float2* __restrict__ msr) {
    if (blockIdx.x < 42) {
        int idx = blockIdx.x * 256 + threadIdx.x;       // (ks*4+q)*64 + lane
        if (idx >= NKSTEP * 4 * 64) return;
        int l  = idx & 63;
        int q  = (idx >> 6) & 3;
        int ks = idx >> 8;
        int n  = q * 16 + (l & 15);
        int kb = ks * 32 + (l >> 4) * 8;
        u32x4 u;
        #pragma unroll
        for (int jj = 0; jj < 4; jj++) {
            unsigned short lo, hi;
            #pragma unroll
            for (int e = 0; e < 2; e++) {
                int k = kb + 2 * jj + e;
                float val;
                if (k < K_ENV) {
                    int t  = k / 640;
                    int rm = k - t * 640;
                    int g  = rm >> 7;
                    int c  = (rm & 127) >> 2;
                    int r  = k & 3;
                    int nu = 4 * g + r;
                    int f  = 2 * c + t;                  // even/odd tile split
                    val = iw[(nu * NF + n) * NF + f];
                } else {
                    val = wself[n * NF + (k - K_ENV)];
                }
                if (e == 0) lo = f2bf(val); else hi = f2bf(val);
            }
            u[jj] = (unsigned)lo | ((unsigned)hi << 16);
        }
        *(u32x4*)&WtB[idx * 8] = u;
    } else if (blockIdx.x < 160) {
        int i = (blockIdx.x - 42) * 256 + threadIdx.x;
        if (i < N_ATOMS) cnts[i] = 0;
    } else {
        int i = threadIdx.x;
        if (i < ND) { float2 m; m.x = mu[i]; m.y = 1.0f / sigma[i]; msr[i] = m; }
    }
}

// ---------------------------------------------------------------------------
// K1: scatter pairs into per-atom buckets; pack (second<<16 | dist_u16).
__global__ void k_scatter(const int* __restrict__ first, const int* __restrict__ second,
                          const float* __restrict__ dist, int* __restrict__ cnts,
                          unsigned* __restrict__ pk) {
    int p = blockIdx.x * 256 + threadIdx.x;
    if (p >= N_PAIRS) return;
    int a = first[p];
    int pos = atomicAdd(&cnts[a], 1);
    if (pos < CAP) {
        float d = dist[p];
        unsigned du = (unsigned)((d - D_LO) * D_SCALE_I + 0.5f);
        du = min(du, 65535u);
        pk[(size_t)a * CAP + pos] = ((unsigned)second[p] << 16) | du;
    }
}

// ---------------------------------------------------------------------------
// K2: fused sense + MFMA envsum + MFMA interaction matmul. 512 thr = 8 waves.
// ALL phase-1 staging lives in ext-vectors / named scalars (no unions, no
// local arrays) so nothing allocas to scratch (R10 lesson: VGPR=40 + 26MB
// scratch traffic = un-promoted stack objects, not register pressure).
// Phase 1: wave w handles atoms {2w,2w+1}. Per 16-pair K-step:
//   A = sense^T (8 exps inline), B = x rows via dwordx2 (features {2cl,2cl+1}
//   -> even/odd tiles), 2x mfma_f32_32x32x16_bf16; C -> LDS in C-layout.
// Phase 2: waves 0..3: out[16 atoms][64] = env[16][1344] x WtB (16x16x32).
__global__ void __launch_bounds__(512, 6)
k_main(const float* __restrict__ x, const int* __restrict__ cnts,
       const unsigned* __restrict__ pk, const float2* __restrict__ msr,
       const unsigned short* __restrict__ WtB, const float* __restrict__ bself,
       float* __restrict__ out) {
    __shared__ unsigned short env[BA * ESTRIDE];          // 43264 B -> 3 blocks/CU
    const int t  = threadIdx.x;
    const int w  = t >> 6;       // wave 0..7
    const int l  = t & 63;       // lane
    const int h  = l >> 5;       // half-wave (k-group)
    const int cl = l & 31;       // A: nu row   |  B/C: column
    const int a0 = blockIdx.x * BA;

    // lane-resident sense constants (nu = cl)
    float2 ms   = msr[min(cl, ND - 1)];
    const float isig  = ms.y;
    const float musig = ms.x * ms.y;
    const bool  nuok  = (cl < ND);
    const float* xb = x + 2 * cl;

    // ---- Phase 1: MFMA envsum (2 atoms per wave, sequential) ----
    #pragma unroll 1
    for (int ci = 0; ci < 2; ci++) {
        const int i = 2 * w + ci;
        const int a = a0 + i;
        const int cnt = min(cnts[a], CAP);
        const int nst = max((cnt + 15) >> 4, 1);
        const unsigned* gb = &pk[(size_t)a * CAP];
        f32x16 acc0 = {0.f}, acc1 = {0.f};
        #pragma unroll 1
        for (int ks = 0; ks < nst; ks++) {
            const int k0 = ks * 16 + h * 8;
            uint4 p0 = *(const uint4*)(gb + k0);          // 16B-aligned, h-uniform
            uint4 p1 = *(const uint4*)(gb + k0 + 4);
            // 8 dwordx2 gathers, named scalars (no array -> no alloca)
            float2 b0 = *(const float2*)&xb[min(p0.x >> 16, NM1) * NF];
            float2 b1 = *(const float2*)&xb[min(p0.y >> 16, NM1) * NF];
            float2 b2 = *(const float2*)&xb[min(p0.z >> 16, NM1) * NF];
            float2 b3 = *(const float2*)&xb[min(p0.w >> 16, NM1) * NF];
            float2 b4 = *(const float2*)&xb[min(p1.x >> 16, NM1) * NF];
            float2 b5 = *(const float2*)&xb[min(p1.y >> 16, NM1) * NF];
            float2 b6 = *(const float2*)&xb[min(p1.z >> 16, NM1) * NF];
            float2 b7 = *(const float2*)&xb[min(p1.w >> 16, NM1) * NF];
            u32x4 A, B0, B1;
            A[0] = pkbf(senseval(p0.x, k0 + 0, cnt, isig, musig, nuok),
                        senseval(p0.y, k0 + 1, cnt, isig, musig, nuok));
            A[1] = pkbf(senseval(p0.z, k0 + 2, cnt, isig, musig, nuok),
                        senseval(p0.w, k0 + 3, cnt, isig, musig, nuok));
            A[2] = pkbf(senseval(p1.x, k0 + 4, cnt, isig, musig, nuok),
                        senseval(p1.y, k0 + 5, cnt, isig, musig, nuok));
            A[3] = pkbf(senseval(p1.z, k0 + 6, cnt, isig, musig, nuok),
                        senseval(p1.w, k0 + 7, cnt, isig, musig, nuok));
            B0[0] = pkbf(b0.x, b1.x); B0[1] = pkbf(b2.x, b3.x);
            B0[2] = pkbf(b4.x, b5.x); B0[3] = pkbf(b6.x, b7.x);   // even feats
            B1[0] = pkbf(b0.y, b1.y); B1[1] = pkbf(b2.y, b3.y);
            B1[2] = pkbf(b4.y, b5.y); B1[3] = pkbf(b6.y, b7.y);   // odd feats
            acc0 = __builtin_amdgcn_mfma_f32_32x32x16_bf16(
                       __builtin_bit_cast(bf16x8, A),
                       __builtin_bit_cast(bf16x8, B0), acc0, 0, 0, 0);
            acc1 = __builtin_amdgcn_mfma_f32_32x32x16_bf16(
                       __builtin_bit_cast(bf16x8, A),
                       __builtin_bit_cast(bf16x8, B1), acc1, 0, 0, 0);
        }
        // C -> env LDS. C row = (reg&3)+8*(reg>>2)+4*h; g=2q+h holds rows
        // 4g..4g+3 (g<5 <=> row<20). k' = t*640 + g*128 + cl*4 + r.
        unsigned short* er = &env[i * ESTRIDE];
        #pragma unroll
        for (int q = 0; q < 3; q++) {
            int g = 2 * q + h;
            if (g < 5) {
                uint2 v0, v1;
                v0.x = pkbf(acc0[4 * q + 0], acc0[4 * q + 1]);
                v0.y = pkbf(acc0[4 * q + 2], acc0[4 * q + 3]);
                v1.x = pkbf(acc1[4 * q + 0], acc1[4 * q + 1]);
                v1.y = pkbf(acc1[4 * q + 2], acc1[4 * q + 3]);
                *(uint2*)&er[g * 128 + cl * 4]       = v0;
                *(uint2*)&er[640 + g * 128 + cl * 4] = v1;
            }
        }
        er[K_ENV + l] = f2bf(x[(size_t)a * NF + l]);      // self features
    }
    __syncthreads();

    // ---- Phase 2: MFMA GEMM (waves 0..3) ----
    if (w < 4) {
        const int m16  = l & 15;     // atom row / out col
        const int quad = l >> 4;
        f32x4 acc = {0.f, 0.f, 0.f, 0.f};
        for (int ks = 0; ks < NKSTEP; ks++) {
            s16x8 afrag = *(const s16x8*)&env[m16 * ESTRIDE + ks * 32 + quad * 8];
            s16x8 bfrag = *(const s16x8*)&WtB[((ks * 4 + w) * 64 + l) * 8];
            acc = __builtin_amdgcn_mfma_f32_16x16x32_bf16(
                      __builtin_bit_cast(bf16x8, afrag),
                      __builtin_bit_cast(bf16x8, bfrag), acc, 0, 0, 0);
        }
        const float bs = bself[w * 16 + m16];
        #pragma unroll
        for (int r = 0; r < 4; r++) {
            int row = quad * 4 + r;                       // atom within block
            out[(size_t)(a0 + row) * NF + w * 16 + m16] = acc[r] + bs;
        }
    }
}

// ---------------------------------------------------------------------------
extern "C" void kernel_launch(void* const* d_in, const int* in_sizes, int n_in,
                              void* d_out, int out_size, void* d_ws, size_t ws_size,
                              hipStream_t stream) {
    const float* x      = (const float*)d_in[0];
    const int*   first  = (const int*)d_in[1];
    const int*   second = (const int*)d_in[2];
    const float* dist   = (const float*)d_in[3];
    const float* mu     = (const float*)d_in[4];
    const float* sigma  = (const float*)d_in[5];
    const float* iw     = (const float*)d_in[6];
    const float* wself  = (const float*)d_in[7];
    const float* bself  = (const float*)d_in[8];
    float* out = (float*)d_out;

    char* ws = (char*)d_ws;
    unsigned short* WtB  = (unsigned short*)(ws);          // 172032 B
    int*            cnts = (int*)(ws + 172032);            // 120000 B
    float2*         msr  = (float2*)(ws + 292032);         // 160 B
    unsigned*       pk   = (unsigned*)(ws + 292192);       // 5760000 B -> ~6.05 MB

    k_prep<<<dim3(161), dim3(256), 0, stream>>>(iw, wself, mu, sigma, WtB, cnts, msr);
    k_scatter<<<dim3((N_PAIRS + 255) / 256), dim3(256), 0, stream>>>(
        first, second, dist, cnts, pk);
    k_main<<<dim3(N_ATOMS / BA), dim3(512), 0, stream>>>(
        x, cnts, pk, msr, WtB, bself, out);
}